// Round 3
// baseline (700.235 us; speedup 1.0000x reference)
//
#include <hip/hip_runtime.h>

// EdgeGCN v2: CSR counting-sort + gather aggregation (no fp32 atomics).
// N=100000 nodes, E=3200000 edges, F_IN=128, HID=16, OUT=1.
//
// ws layout (4B units):
//   cnt   [0, N)            uint   in-degree counts (memset 0)
//   dinv  [N, 2N)           float  rsqrt(deg+1)
//   ptr   [2N, 3N+1]        int    CSR row offsets (by dst)
//   cur   [3N+2, 4N+2)      int    fill cursors (copy of ptr)
//   bsum  [4N+2, 4N+2+256)  uint   scan block sums
//   sidx  [..., +E)         int    sorted src indices (grouped by dst)
//   S     [+16N)            float  s1=(x@W1)*dinv, then s2=(h1@W2)*dinv
//   AGG   [+16N)            float  gather output (also reused as scan temp 'pre')
//   UV    [+2N)             float2 per-node (u,v)
// total ~ 38N + E + 258 elems = ~28 MB.

constexpr int NN = 100000;
constexpr int NE = 3200000;
constexpr int FI = 128;
constexpr int HD = 16;
constexpr int SCAN_B = 512;                       // elems per scan block
constexpr int NBLK = (NN + SCAN_B - 1) / SCAN_B;  // 196

__global__ __launch_bounds__(256) void k_deg(const int* __restrict__ dst,
                                             unsigned* __restrict__ cnt) {
    int t = blockIdx.x * 256 + threadIdx.x;       // NE/4 threads
    int4 d4 = reinterpret_cast<const int4*>(dst)[t];
    atomicAdd(&cnt[d4.x], 1u);
    atomicAdd(&cnt[d4.y], 1u);
    atomicAdd(&cnt[d4.z], 1u);
    atomicAdd(&cnt[d4.w], 1u);
}

// Per-block exclusive scan of cnt -> pre, block totals -> bsum, dinv fused.
__global__ __launch_bounds__(256) void k_scanA(const unsigned* __restrict__ cnt,
                                               unsigned* __restrict__ pre,
                                               unsigned* __restrict__ bsum,
                                               float* __restrict__ dinv) {
    __shared__ unsigned tsum[256];
    int t = threadIdx.x;
    int base = blockIdx.x * SCAN_B;
    int i0 = base + 2 * t, i1 = base + 2 * t + 1;
    unsigned a = (i0 < NN) ? cnt[i0] : 0u;
    unsigned b = (i1 < NN) ? cnt[i1] : 0u;
    if (i0 < NN) dinv[i0] = rsqrtf((float)a + 1.0f);
    if (i1 < NN) dinv[i1] = rsqrtf((float)b + 1.0f);
    tsum[t] = a + b;
    __syncthreads();
    #pragma unroll
    for (int off = 1; off < 256; off <<= 1) {
        unsigned v = (t >= off) ? tsum[t - off] : 0u;
        __syncthreads();
        tsum[t] += v;
        __syncthreads();
    }
    unsigned excl = tsum[t] - (a + b);
    if (t == 255) bsum[blockIdx.x] = tsum[255];
    if (i0 < NN) pre[i0] = excl;
    if (i1 < NN) pre[i1] = excl + a;
}

// Exclusive scan of bsum[NBLK] in place (single block).
__global__ __launch_bounds__(256) void k_scanB(unsigned* __restrict__ bsum) {
    __shared__ unsigned tsum[256];
    int t = threadIdx.x;
    unsigned v = (t < NBLK) ? bsum[t] : 0u;
    tsum[t] = v;
    __syncthreads();
    #pragma unroll
    for (int off = 1; off < 256; off <<= 1) {
        unsigned w = (t >= off) ? tsum[t - off] : 0u;
        __syncthreads();
        tsum[t] += w;
        __syncthreads();
    }
    if (t < NBLK) bsum[t] = tsum[t] - v;
}

// ptr[i] = pre[i] + bsum[i/512]; ptr[N] = E; cur = ptr.
__global__ __launch_bounds__(256) void k_scanC(const unsigned* __restrict__ pre,
                                               const unsigned* __restrict__ bsum,
                                               int* __restrict__ ptr,
                                               int* __restrict__ cur) {
    int i = blockIdx.x * 256 + threadIdx.x;       // N+1 threads
    if (i > NN) return;
    int v = (i == NN) ? NE : (int)(pre[i] + bsum[i >> 9]);
    ptr[i] = v;
    cur[i] = v;
}

__global__ __launch_bounds__(256) void k_fill(const int* __restrict__ src,
                                              const int* __restrict__ dst,
                                              int* __restrict__ cur,
                                              int* __restrict__ sidx) {
    int e = blockIdx.x * 256 + threadIdx.x;       // NE threads
    int d = dst[e];
    int s = src[e];
    int pos = atomicAdd(&cur[d], 1);
    sidx[pos] = s;
}

// S = (x @ W1) * dinv -- one thread per node, W1 thread-uniform (SGPR loads)
__global__ __launch_bounds__(256) void k_xw1(const float* __restrict__ x,
                                             const float* __restrict__ W1,
                                             const float* __restrict__ dinv,
                                             float* __restrict__ S) {
    int i = blockIdx.x * 256 + threadIdx.x;
    if (i >= NN) return;
    const float4* xr = reinterpret_cast<const float4*>(x + (size_t)i * FI);
    float acc[HD];
    #pragma unroll
    for (int k = 0; k < HD; ++k) acc[k] = 0.f;
    #pragma unroll 8
    for (int jc = 0; jc < FI / 4; ++jc) {
        float4 xv = xr[jc];
        const float* w = W1 + jc * 4 * HD;
        #pragma unroll
        for (int k = 0; k < HD; ++k)
            acc[k] += xv.x * w[k] + xv.y * w[HD + k] + xv.z * w[2 * HD + k] + xv.w * w[3 * HD + k];
    }
    float dv = dinv[i];
    float4* out = reinterpret_cast<float4*>(S + (size_t)i * HD);
    #pragma unroll
    for (int q = 0; q < 4; ++q)
        out[q] = make_float4(acc[q * 4 + 0] * dv, acc[q * 4 + 1] * dv,
                             acc[q * 4 + 2] * dv, acc[q * 4 + 3] * dv);
}

// AGG[i] = sum over incoming edges of S[sidx[j]] -- 16 lanes per node.
__global__ __launch_bounds__(256) void k_gather(const int* __restrict__ ptr,
                                                const int* __restrict__ sidx,
                                                const float* __restrict__ S,
                                                float* __restrict__ AGG) {
    int t = blockIdx.x * 256 + threadIdx.x;       // NN*16 threads (6250 blocks)
    int i = t >> 4;
    int k = t & 15;
    int p0 = ptr[i], p1 = ptr[i + 1];
    float a0 = 0.f, a1 = 0.f;
    int j = p0;
    for (; j + 1 < p1; j += 2) {
        int s0 = sidx[j];
        int s1 = sidx[j + 1];
        a0 += S[(size_t)s0 * HD + k];
        a1 += S[(size_t)s1 * HD + k];
    }
    if (j < p1) a0 += S[(size_t)sidx[j] * HD + k];
    AGG[(size_t)i * HD + k] = a0 + a1;
}

// h1 = relu(dinv*(AGG + S) + b1); S <- (h1 @ W2) * dinv
__global__ __launch_bounds__(256) void k_h1s2(const float* __restrict__ AGG,
                                              float* __restrict__ S,
                                              const float* __restrict__ dinv,
                                              const float* __restrict__ b1,
                                              const float* __restrict__ W2) {
    int i = blockIdx.x * 256 + threadIdx.x;
    if (i >= NN) return;
    float dv = dinv[i];
    const float4* ar = reinterpret_cast<const float4*>(AGG + (size_t)i * HD);
    float4* sr = reinterpret_cast<float4*>(S + (size_t)i * HD);
    float h[HD];
    #pragma unroll
    for (int q = 0; q < 4; ++q) {
        float4 a = ar[q];
        float4 s = sr[q];
        h[q * 4 + 0] = fmaxf(dv * (a.x + s.x) + b1[q * 4 + 0], 0.f);
        h[q * 4 + 1] = fmaxf(dv * (a.y + s.y) + b1[q * 4 + 1], 0.f);
        h[q * 4 + 2] = fmaxf(dv * (a.z + s.z) + b1[q * 4 + 2], 0.f);
        h[q * 4 + 3] = fmaxf(dv * (a.w + s.w) + b1[q * 4 + 3], 0.f);
    }
    float acc[HD];
    #pragma unroll
    for (int k = 0; k < HD; ++k) acc[k] = 0.f;
    #pragma unroll
    for (int j = 0; j < HD; ++j) {
        float hj = h[j];
        #pragma unroll
        for (int k = 0; k < HD; ++k) acc[k] += hj * W2[j * HD + k];
    }
    #pragma unroll
    for (int q = 0; q < 4; ++q)
        sr[q] = make_float4(acc[q * 4 + 0] * dv, acc[q * 4 + 1] * dv,
                            acc[q * 4 + 2] * dv, acc[q * 4 + 3] * dv);
}

// h2 = dinv*(AGG + S) + b2; UV[i] = (h2 . Wfc[0:16], h2 . Wfc[16:32])
__global__ __launch_bounds__(256) void k_uv(const float* __restrict__ AGG,
                                            const float* __restrict__ S,
                                            const float* __restrict__ dinv,
                                            const float* __restrict__ b2,
                                            const float* __restrict__ Wfc,
                                            float2* __restrict__ UV) {
    int i = blockIdx.x * 256 + threadIdx.x;
    if (i >= NN) return;
    float dv = dinv[i];
    const float4* ar = reinterpret_cast<const float4*>(AGG + (size_t)i * HD);
    const float4* sr = reinterpret_cast<const float4*>(S + (size_t)i * HD);
    float u = 0.f, v = 0.f;
    #pragma unroll
    for (int q = 0; q < 4; ++q) {
        float4 a = ar[q];
        float4 s = sr[q];
        float h0 = dv * (a.x + s.x) + b2[q * 4 + 0];
        float h1 = dv * (a.y + s.y) + b2[q * 4 + 1];
        float h2 = dv * (a.z + s.z) + b2[q * 4 + 2];
        float h3 = dv * (a.w + s.w) + b2[q * 4 + 3];
        u += h0 * Wfc[q * 4 + 0] + h1 * Wfc[q * 4 + 1] + h2 * Wfc[q * 4 + 2] + h3 * Wfc[q * 4 + 3];
        v += h0 * Wfc[HD + q * 4 + 0] + h1 * Wfc[HD + q * 4 + 1] + h2 * Wfc[HD + q * 4 + 2] + h3 * Wfc[HD + q * 4 + 3];
    }
    UV[i] = make_float2(u, v);
}

__global__ __launch_bounds__(256) void k_pred(const int* __restrict__ src,
                                              const int* __restrict__ dst,
                                              const float2* __restrict__ UV,
                                              const float* __restrict__ bfc,
                                              float* __restrict__ out) {
    int t = blockIdx.x * 256 + threadIdx.x;       // NE/4 threads
    int4 s4 = reinterpret_cast<const int4*>(src)[t];
    int4 d4 = reinterpret_cast<const int4*>(dst)[t];
    float bb = bfc[0];
    float4 o;
    o.x = UV[s4.x].x + UV[d4.x].y + bb;
    o.y = UV[s4.y].x + UV[d4.y].y + bb;
    o.z = UV[s4.z].x + UV[d4.z].y + bb;
    o.w = UV[s4.w].x + UV[d4.w].y + bb;
    reinterpret_cast<float4*>(out)[t] = o;
}

extern "C" void kernel_launch(void* const* d_in, const int* in_sizes, int n_in,
                              void* d_out, int out_size, void* d_ws, size_t ws_size,
                              hipStream_t stream) {
    const float* x   = (const float*)d_in[0];
    const int*   ei  = (const int*)d_in[1];
    const float* W1  = (const float*)d_in[2];
    const float* b1  = (const float*)d_in[3];
    const float* W2  = (const float*)d_in[4];
    const float* b2  = (const float*)d_in[5];
    const float* Wfc = (const float*)d_in[6];
    const float* bfc = (const float*)d_in[7];
    const int* src = ei;            // edge_index[0]
    const int* dst = ei + NE;       // edge_index[1]

    char* ws = (char*)d_ws;
    unsigned* cnt  = (unsigned*)ws;                         // N
    float*    dinv = (float*)(ws + sizeof(float) * (size_t)NN);          // N
    int*      ptr  = (int*)(ws + sizeof(float) * (size_t)(2 * NN));      // N+1
    int*      cur  = (int*)(ws + sizeof(float) * (size_t)(3 * NN + 2));  // N
    unsigned* bsum = (unsigned*)(ws + sizeof(float) * (size_t)(4 * NN + 2)); // 256
    int*      sidx = (int*)(ws + sizeof(float) * (size_t)(4 * NN + 258));    // E
    float*    S    = (float*)(ws + sizeof(float) * ((size_t)(4 * NN + 258) + NE));        // 16N
    float*    AGG  = (float*)(ws + sizeof(float) * ((size_t)(4 * NN + 258) + NE + 16 * (size_t)NN)); // 16N
    float2*   UV   = (float2*)(ws + sizeof(float) * ((size_t)(4 * NN + 258) + NE + 32 * (size_t)NN)); // 2N
    float* out = (float*)d_out;
    unsigned* pre = (unsigned*)AGG;   // scan temp overlays AGG (freed before gather)

    hipMemsetAsync(cnt, 0, NN * sizeof(unsigned), stream);

    k_deg  <<<NE / 4 / 256, 256, 0, stream>>>(dst, cnt);
    k_scanA<<<NBLK, 256, 0, stream>>>(cnt, pre, bsum, dinv);
    k_scanB<<<1, 256, 0, stream>>>(bsum);
    k_scanC<<<(NN + 256) / 256, 256, 0, stream>>>(pre, bsum, ptr, cur);
    k_fill <<<NE / 256, 256, 0, stream>>>(src, dst, cur, sidx);
    k_xw1  <<<(NN + 255) / 256, 256, 0, stream>>>(x, W1, dinv, S);
    k_gather<<<NN * HD / 256, 256, 0, stream>>>(ptr, sidx, S, AGG);
    k_h1s2 <<<(NN + 255) / 256, 256, 0, stream>>>(AGG, S, dinv, b1, W2);
    k_gather<<<NN * HD / 256, 256, 0, stream>>>(ptr, sidx, S, AGG);
    k_uv   <<<(NN + 255) / 256, 256, 0, stream>>>(AGG, S, dinv, b2, Wfc, UV);
    k_pred <<<NE / 4 / 256, 256, 0, stream>>>(src, dst, UV, bfc, out);
}

// Round 4
// 356.924 us; speedup vs baseline: 1.9619x; 1.9619x over previous
//
#include <hip/hip_runtime.h>

// EdgeGCN v3: atomic-free counting sort (block multi-split) + CSR gather.
// N=100000, E=3200000, F_IN=128, HID=16, OUT=1.
//
// Pipeline: hist -> scan(A,B,C) -> part -> fine(sidx,ptr,dinv) -> xw1 ->
//           gather -> h1s2 -> gather -> uv -> pred.   No global atomics.

constexpr int NN = 100000;
constexpr int NE = 3200000;
constexpr int FI = 128;
constexpr int HD = 16;
constexpr int SHIFT = 7;                    // 128 nodes per coarse bucket
constexpr int KB = (NN + 127) >> 7;         // 782 buckets
constexpr int GPART = 256;                  // partition blocks
constexpr int CH = NE / GPART;              // 12500 edges per block (exact)
constexpr int M = KB * GPART;               // 200192 histogram entries
constexpr int NBLK1 = (M + 511) / 512;      // 391 scan blocks (exact: 512*391=M)

// Per-block LDS histogram of coarse buckets, written transposed HT[k*G+b].
__global__ __launch_bounds__(256) void k_hist(const int* __restrict__ dst,
                                              unsigned* __restrict__ HT) {
    __shared__ unsigned cnt[KB];
    for (int i = threadIdx.x; i < KB; i += 256) cnt[i] = 0;
    __syncthreads();
    const int base = blockIdx.x * CH;
    for (int j = threadIdx.x; j < CH; j += 256)
        atomicAdd(&cnt[dst[base + j] >> SHIFT], 1u);
    __syncthreads();
    for (int k = threadIdx.x; k < KB; k += 256)
        HT[(size_t)k * GPART + blockIdx.x] = cnt[k];
}

// Exclusive scan, stage A: per-512-block scan of in[n] -> pre, totals -> bs.
__global__ __launch_bounds__(256) void k_scanA(const unsigned* __restrict__ in,
                                               unsigned* __restrict__ pre,
                                               unsigned* __restrict__ bs, int n) {
    __shared__ unsigned tsum[256];
    int t = threadIdx.x;
    int base = blockIdx.x * 512;
    int i0 = base + 2 * t, i1 = i0 + 1;
    unsigned a = (i0 < n) ? in[i0] : 0u;
    unsigned b = (i1 < n) ? in[i1] : 0u;
    tsum[t] = a + b;
    __syncthreads();
    #pragma unroll
    for (int off = 1; off < 256; off <<= 1) {
        unsigned v = (t >= off) ? tsum[t - off] : 0u;
        __syncthreads();
        tsum[t] += v;
        __syncthreads();
    }
    unsigned excl = tsum[t] - (a + b);
    if (t == 255) bs[blockIdx.x] = tsum[255];
    if (i0 < n) pre[i0] = excl;
    if (i1 < n) pre[i1] = excl + a;
}

// Stage B: exclusive scan of bs[nb] (nb <= 512) in place.
__global__ __launch_bounds__(512) void k_scanB(unsigned* __restrict__ bs, int nb) {
    __shared__ unsigned tsum[512];
    int t = threadIdx.x;
    unsigned v = (t < nb) ? bs[t] : 0u;
    tsum[t] = v;
    __syncthreads();
    #pragma unroll
    for (int off = 1; off < 512; off <<= 1) {
        unsigned w = (t >= off) ? tsum[t - off] : 0u;
        __syncthreads();
        tsum[t] += w;
        __syncthreads();
    }
    if (t < nb) bs[t] = tsum[t] - v;
}

// Stage C: out[i] = pre[i] + bs[i/512]  (out = HT in place: global START).
__global__ __launch_bounds__(256) void k_scanC(const unsigned* __restrict__ pre,
                                               const unsigned* __restrict__ bs,
                                               unsigned* __restrict__ out, int n) {
    int i = blockIdx.x * 256 + threadIdx.x;
    if (i < n) out[i] = pre[i] + bs[i >> 9];
}

// Partition: block b places its CH edges into bucket-grouped EP via LDS cursors.
// EP entry packs (d & 127) << 17 | s   (s < 2^17).
__global__ __launch_bounds__(256) void k_part(const int* __restrict__ src,
                                              const int* __restrict__ dst,
                                              const unsigned* __restrict__ HT,
                                              unsigned* __restrict__ EP) {
    __shared__ unsigned cur[KB];
    int b = blockIdx.x;
    for (int k = threadIdx.x; k < KB; k += 256)
        cur[k] = HT[(size_t)k * GPART + b];
    __syncthreads();
    const int base = b * CH;
    for (int j = threadIdx.x; j < CH; j += 256) {
        int d = dst[base + j];
        int s = src[base + j];
        unsigned pos = atomicAdd(&cur[d >> SHIFT], 1u);
        EP[pos] = ((unsigned)(d & 127) << 17) | (unsigned)s;
    }
}

// Fine sort: one block per bucket. Produces sidx (src grouped by dst),
// ptr (CSR offsets), dinv. All counting via LDS.
__global__ __launch_bounds__(256) void k_fine(const unsigned* __restrict__ HT,
                                              const unsigned* __restrict__ EP,
                                              int* __restrict__ sidx,
                                              int* __restrict__ ptr,
                                              float* __restrict__ dinv) {
    __shared__ unsigned cnt[128];
    __shared__ unsigned off[128];
    int k = blockIdx.x;
    int s0 = (int)HT[(size_t)k * GPART];
    int s1 = (k == KB - 1) ? NE : (int)HT[(size_t)(k + 1) * GPART];
    if (threadIdx.x < 128) cnt[threadIdx.x] = 0;
    __syncthreads();
    for (int j = s0 + (int)threadIdx.x; j < s1; j += 256)
        atomicAdd(&cnt[EP[j] >> 17], 1u);
    __syncthreads();
    if (threadIdx.x < 128) off[threadIdx.x] = cnt[threadIdx.x];
    __syncthreads();
    #pragma unroll
    for (int o = 1; o < 128; o <<= 1) {
        unsigned v = 0;
        if (threadIdx.x < 128 && threadIdx.x >= o) v = off[threadIdx.x - o];
        __syncthreads();
        if (threadIdx.x < 128) off[threadIdx.x] += v;  // inclusive scan
        __syncthreads();
    }
    int n0 = k << SHIFT;
    if (threadIdx.x < 128) {
        int n = n0 + (int)threadIdx.x;
        if (n < NN) {
            ptr[n] = s0 + (int)(off[threadIdx.x] - cnt[threadIdx.x]);
            dinv[n] = rsqrtf((float)cnt[threadIdx.x] + 1.0f);
        }
    }
    if (k == KB - 1 && threadIdx.x == 0) ptr[NN] = NE;
    __syncthreads();
    if (threadIdx.x < 128)
        cnt[threadIdx.x] = (unsigned)s0 + off[threadIdx.x] - cnt[threadIdx.x];  // cursors
    __syncthreads();
    for (int j = s0 + (int)threadIdx.x; j < s1; j += 256) {
        unsigned p = EP[j];
        unsigned pos = atomicAdd(&cnt[p >> 17], 1u);
        sidx[pos] = (int)(p & 0x1FFFFu);
    }
}

// S = (x @ W1) * dinv
__global__ __launch_bounds__(256) void k_xw1(const float* __restrict__ x,
                                             const float* __restrict__ W1,
                                             const float* __restrict__ dinv,
                                             float* __restrict__ S) {
    int i = blockIdx.x * 256 + threadIdx.x;
    if (i >= NN) return;
    const float4* xr = reinterpret_cast<const float4*>(x + (size_t)i * FI);
    float acc[HD];
    #pragma unroll
    for (int k = 0; k < HD; ++k) acc[k] = 0.f;
    #pragma unroll 8
    for (int jc = 0; jc < FI / 4; ++jc) {
        float4 xv = xr[jc];
        const float* w = W1 + jc * 4 * HD;
        #pragma unroll
        for (int k = 0; k < HD; ++k)
            acc[k] += xv.x * w[k] + xv.y * w[HD + k] + xv.z * w[2 * HD + k] + xv.w * w[3 * HD + k];
    }
    float dv = dinv[i];
    float4* out = reinterpret_cast<float4*>(S + (size_t)i * HD);
    #pragma unroll
    for (int q = 0; q < 4; ++q)
        out[q] = make_float4(acc[q * 4 + 0] * dv, acc[q * 4 + 1] * dv,
                             acc[q * 4 + 2] * dv, acc[q * 4 + 3] * dv);
}

// AGG[i] = sum_{j in ptr[i]..ptr[i+1]} S[sidx[j]] -- 16 lanes per node, x4 unroll.
__global__ __launch_bounds__(256) void k_gather(const int* __restrict__ ptr,
                                                const int* __restrict__ sidx,
                                                const float* __restrict__ S,
                                                float* __restrict__ AGG) {
    int t = blockIdx.x * 256 + threadIdx.x;       // NN*16 threads
    int i = t >> 4;
    int kk = t & 15;
    int p0 = ptr[i], p1 = ptr[i + 1];
    float a0 = 0.f, a1 = 0.f, a2 = 0.f, a3 = 0.f;
    int j = p0;
    for (; j + 3 < p1; j += 4) {
        int v0 = sidx[j], v1 = sidx[j + 1], v2 = sidx[j + 2], v3 = sidx[j + 3];
        a0 += S[(size_t)v0 * HD + kk];
        a1 += S[(size_t)v1 * HD + kk];
        a2 += S[(size_t)v2 * HD + kk];
        a3 += S[(size_t)v3 * HD + kk];
    }
    for (; j < p1; ++j) a0 += S[(size_t)sidx[j] * HD + kk];
    AGG[(size_t)i * HD + kk] = (a0 + a1) + (a2 + a3);
}

// h1 = relu(dinv*(AGG + S) + b1); S <- (h1 @ W2) * dinv
__global__ __launch_bounds__(256) void k_h1s2(const float* __restrict__ AGG,
                                              float* __restrict__ S,
                                              const float* __restrict__ dinv,
                                              const float* __restrict__ b1,
                                              const float* __restrict__ W2) {
    int i = blockIdx.x * 256 + threadIdx.x;
    if (i >= NN) return;
    float dv = dinv[i];
    const float4* ar = reinterpret_cast<const float4*>(AGG + (size_t)i * HD);
    float4* sr = reinterpret_cast<float4*>(S + (size_t)i * HD);
    float h[HD];
    #pragma unroll
    for (int q = 0; q < 4; ++q) {
        float4 a = ar[q];
        float4 s = sr[q];
        h[q * 4 + 0] = fmaxf(dv * (a.x + s.x) + b1[q * 4 + 0], 0.f);
        h[q * 4 + 1] = fmaxf(dv * (a.y + s.y) + b1[q * 4 + 1], 0.f);
        h[q * 4 + 2] = fmaxf(dv * (a.z + s.z) + b1[q * 4 + 2], 0.f);
        h[q * 4 + 3] = fmaxf(dv * (a.w + s.w) + b1[q * 4 + 3], 0.f);
    }
    float acc[HD];
    #pragma unroll
    for (int k = 0; k < HD; ++k) acc[k] = 0.f;
    #pragma unroll
    for (int j = 0; j < HD; ++j) {
        float hj = h[j];
        #pragma unroll
        for (int k = 0; k < HD; ++k) acc[k] += hj * W2[j * HD + k];
    }
    #pragma unroll
    for (int q = 0; q < 4; ++q)
        sr[q] = make_float4(acc[q * 4 + 0] * dv, acc[q * 4 + 1] * dv,
                            acc[q * 4 + 2] * dv, acc[q * 4 + 3] * dv);
}

// h2 = dinv*(AGG + S) + b2; UV[i] = (h2 . Wfc[0:16], h2 . Wfc[16:32])
__global__ __launch_bounds__(256) void k_uv(const float* __restrict__ AGG,
                                            const float* __restrict__ S,
                                            const float* __restrict__ dinv,
                                            const float* __restrict__ b2,
                                            const float* __restrict__ Wfc,
                                            float2* __restrict__ UV) {
    int i = blockIdx.x * 256 + threadIdx.x;
    if (i >= NN) return;
    float dv = dinv[i];
    const float4* ar = reinterpret_cast<const float4*>(AGG + (size_t)i * HD);
    const float4* sr = reinterpret_cast<const float4*>(S + (size_t)i * HD);
    float u = 0.f, v = 0.f;
    #pragma unroll
    for (int q = 0; q < 4; ++q) {
        float4 a = ar[q];
        float4 s = sr[q];
        float h0 = dv * (a.x + s.x) + b2[q * 4 + 0];
        float h1 = dv * (a.y + s.y) + b2[q * 4 + 1];
        float h2 = dv * (a.z + s.z) + b2[q * 4 + 2];
        float h3 = dv * (a.w + s.w) + b2[q * 4 + 3];
        u += h0 * Wfc[q * 4 + 0] + h1 * Wfc[q * 4 + 1] + h2 * Wfc[q * 4 + 2] + h3 * Wfc[q * 4 + 3];
        v += h0 * Wfc[HD + q * 4 + 0] + h1 * Wfc[HD + q * 4 + 1] + h2 * Wfc[HD + q * 4 + 2] + h3 * Wfc[HD + q * 4 + 3];
    }
    UV[i] = make_float2(u, v);
}

__global__ __launch_bounds__(256) void k_pred(const int* __restrict__ src,
                                              const int* __restrict__ dst,
                                              const float2* __restrict__ UV,
                                              const float* __restrict__ bfc,
                                              float* __restrict__ out) {
    int t = blockIdx.x * 256 + threadIdx.x;       // NE/4 threads
    int4 s4 = reinterpret_cast<const int4*>(src)[t];
    int4 d4 = reinterpret_cast<const int4*>(dst)[t];
    float bb = bfc[0];
    float4 o;
    o.x = UV[s4.x].x + UV[d4.x].y + bb;
    o.y = UV[s4.y].x + UV[d4.y].y + bb;
    o.z = UV[s4.z].x + UV[d4.z].y + bb;
    o.w = UV[s4.w].x + UV[d4.w].y + bb;
    reinterpret_cast<float4*>(out)[t] = o;
}

extern "C" void kernel_launch(void* const* d_in, const int* in_sizes, int n_in,
                              void* d_out, int out_size, void* d_ws, size_t ws_size,
                              hipStream_t stream) {
    const float* x   = (const float*)d_in[0];
    const int*   ei  = (const int*)d_in[1];
    const float* W1  = (const float*)d_in[2];
    const float* b1  = (const float*)d_in[3];
    const float* W2  = (const float*)d_in[4];
    const float* b2  = (const float*)d_in[5];
    const float* Wfc = (const float*)d_in[6];
    const float* bfc = (const float*)d_in[7];
    const int* src = ei;            // edge_index[0]
    const int* dst = ei + NE;       // edge_index[1]

    // ws layout (4B units):
    //   HT[M] | BS[512] | EP[E] | sidx[E] | ptr[N+2] | dinv[N] | S[16N] | AGG[16N] | UV[2N]
    unsigned* ws32 = (unsigned*)d_ws;
    unsigned* HT   = ws32;
    unsigned* BS   = HT + M;
    unsigned* EP   = BS + 512;
    int*      sidx = (int*)(EP + NE);
    int*      ptr  = sidx + NE;
    float*    dinv = (float*)(ptr + NN + 2);
    float*    S    = dinv + NN;
    float*    AGG  = S + 16 * (size_t)NN;
    float2*   UV   = (float2*)(AGG + 16 * (size_t)NN);
    unsigned* PRE  = (unsigned*)AGG;   // scan temp overlays AGG (dead until gather)
    float* out = (float*)d_out;

    k_hist <<<GPART, 256, 0, stream>>>(dst, HT);
    k_scanA<<<NBLK1, 256, 0, stream>>>(HT, PRE, BS, M);
    k_scanB<<<1, 512, 0, stream>>>(BS, NBLK1);
    k_scanC<<<(M + 255) / 256, 256, 0, stream>>>(PRE, BS, HT, M);
    k_part <<<GPART, 256, 0, stream>>>(src, dst, HT, EP);
    k_fine <<<KB, 256, 0, stream>>>(HT, EP, sidx, ptr, dinv);
    k_xw1  <<<(NN + 255) / 256, 256, 0, stream>>>(x, W1, dinv, S);
    k_gather<<<NN * HD / 256, 256, 0, stream>>>(ptr, sidx, S, AGG);
    k_h1s2 <<<(NN + 255) / 256, 256, 0, stream>>>(AGG, S, dinv, b1, W2);
    k_gather<<<NN * HD / 256, 256, 0, stream>>>(ptr, sidx, S, AGG);
    k_uv   <<<(NN + 255) / 256, 256, 0, stream>>>(AGG, S, dinv, b2, Wfc, UV);
    k_pred <<<NE / 4 / 256, 256, 0, stream>>>(src, dst, UV, bfc, out);
}